// Round 5
// baseline (419.183 us; speedup 1.0000x reference)
//
#include <hip/hip_runtime.h>
#include <math.h>

#define H    24
#define Dh   128
#define LIMG 2048
#define LIP  512
#define DM   3072
#define DIP  1280
#define LK   2560
#define EPSF 1e-6f
#define SM_SCALE 0.08838834764831845f  // 1/sqrt(128)
#define C2EXP 0.12751930f              // SM_SCALE * log2(e)
#define THRU 90.50967f                 // 8 / SM_SCALE (defer-max threshold, unscaled)

#define EXP2F(x) __builtin_exp2f(x)    // lowers to v_exp_f32 (HW is base-2)

typedef __attribute__((ext_vector_type(8))) short bf16x8;
typedef __attribute__((ext_vector_type(4))) float f32x4;

typedef const unsigned int __attribute__((address_space(1))) gu32;
typedef unsigned int __attribute__((address_space(3))) lu32;

static __device__ __forceinline__ unsigned short f2bf(float x) {
  union { float f; unsigned u; } v; v.f = x;
  unsigned r = v.u + 0x7fffu + ((v.u >> 16) & 1u);  // RNE
  return (unsigned short)(r >> 16);
}

static __device__ __forceinline__ float bf2f(unsigned short b) {
  union { unsigned u; float f; } v; v.u = ((unsigned)b) << 16;
  return v.f;
}

// ---------------- Kernel 1: e = silu(t_emb) @ w_ada^T + b_ada ----------------
__global__ __launch_bounds__(256) void ada_kernel(
    const float* __restrict__ t_emb, const float* __restrict__ w_ada,
    const float* __restrict__ b_ada, float* __restrict__ e) {
  int j = blockIdx.x;
  int tid = threadIdx.x;
  const float* wrow = w_ada + (long)j * DIP;
  float acc = 0.f;
  for (int k = tid; k < DIP; k += 256) {
    float t = t_emb[k];
    acc += (t / (1.f + expf(-t))) * wrow[k];
  }
#pragma unroll
  for (int m = 1; m < 64; m <<= 1) acc += __shfl_xor(acc, m, 64);
  __shared__ float red[4];
  if ((tid & 63) == 0) red[tid >> 6] = acc;
  __syncthreads();
  if (tid == 0) e[j] = red[0] + red[1] + red[2] + red[3] + b_ada[j];
}

// ---------------- Kernel 2: AdaLayerNorm -> ip_norm as bf16 hi/lo planes ----
__global__ __launch_bounds__(256) void adaln_kernel(
    const float* __restrict__ x, const float* __restrict__ e,
    unsigned short* __restrict__ ipnh, unsigned short* __restrict__ ipnl) {
  int r = blockIdx.x;
  int tid = threadIdx.x;
  const float* xr = x + (long)r * DIP;
  float v[5];
  float s = 0.f, ss = 0.f;
#pragma unroll
  for (int i = 0; i < 5; i++) {
    v[i] = xr[tid + i * 256];
    s += v[i];
    ss += v[i] * v[i];
  }
#pragma unroll
  for (int m = 1; m < 64; m <<= 1) {
    s += __shfl_xor(s, m, 64);
    ss += __shfl_xor(ss, m, 64);
  }
  __shared__ float rs_[4], rss_[4];
  if ((tid & 63) == 0) { rs_[tid >> 6] = s; rss_[tid >> 6] = ss; }
  __syncthreads();
  s = rs_[0] + rs_[1] + rs_[2] + rs_[3];
  ss = rss_[0] + rss_[1] + rss_[2] + rss_[3];
  float mu = s * (1.f / DIP);
  float var = ss * (1.f / DIP) - mu * mu;
  float rstd = rsqrtf(var + EPSF);
  unsigned short* oh = ipnh + (long)r * DIP;
  unsigned short* ol = ipnl + (long)r * DIP;
#pragma unroll
  for (int i = 0; i < 5; i++) {
    int c = tid + i * 256;
    float o = (v[i] - mu) * rstd * (1.f + e[DIP + c]) + e[c];
    unsigned short hb = f2bf(o);
    oh[c] = hb;
    ol[c] = f2bf(o - bf2f(hb));
  }
}

// ---------------- Kernel 3: img K (RMS) -> Kb bf16, img V -> Vt bf16 (tiled) --
// Kb[H][LK][128]; Vt tiled: [H][LK/32 tiles][128 d][32 cols] (8 KB contiguous tiles).
__global__ __launch_bounds__(256) void prep_kernel(
    const float* __restrict__ k_in, const float* __restrict__ v_in,
    const float* __restrict__ g_k,
    unsigned short* __restrict__ Kb, unsigned short* __restrict__ Vt) {
  __shared__ unsigned short Vls[128][33];
  int h = blockIdx.y, l0 = blockIdx.x * 32;
  int tid = threadIdx.x;
  int r = tid >> 3, c = tid & 7;   // 8 threads/row, 16 elems each
  const float* ksrc = k_in + (long)(l0 + r) * DM + h * Dh + c * 16;
  const float* vsrc = v_in + (long)(l0 + r) * DM + h * Dh + c * 16;
  float kv[16], vv[16];
  float ssq = 0.f;
#pragma unroll
  for (int i = 0; i < 4; i++) {
    float4 a = *(const float4*)(ksrc + i * 4);
    float4 b = *(const float4*)(vsrc + i * 4);
    kv[i*4+0]=a.x; kv[i*4+1]=a.y; kv[i*4+2]=a.z; kv[i*4+3]=a.w;
    vv[i*4+0]=b.x; vv[i*4+1]=b.y; vv[i*4+2]=b.z; vv[i*4+3]=b.w;
    ssq += a.x*a.x + a.y*a.y + a.z*a.z + a.w*a.w;
  }
  ssq += __shfl_xor(ssq, 1, 8);
  ssq += __shfl_xor(ssq, 2, 8);
  ssq += __shfl_xor(ssq, 4, 8);
  float rstd = rsqrtf(ssq * (1.f / Dh) + EPSF);
  unsigned short kb[16];
#pragma unroll
  for (int i = 0; i < 16; i++) kb[i] = f2bf(kv[i] * rstd * g_k[c * 16 + i]);
  unsigned short* kdst = Kb + ((long)h * LK + l0 + r) * Dh + c * 16;
  *(uint4*)(kdst) = *(uint4*)(kb);
  *(uint4*)(kdst + 8) = *(uint4*)(kb + 8);
  // transpose V through LDS
#pragma unroll
  for (int i = 0; i < 16; i++) Vls[c * 16 + i][r] = f2bf(vv[i]);
  __syncthreads();
  if (tid < 128) {   // one thread per d-row: 64B store, tile-contiguous dest
    int d = tid;
    unsigned short ov[32];
#pragma unroll
    for (int j = 0; j < 32; j++) ov[j] = Vls[d][j];
    unsigned short* vdst = Vt + ((long)h * 80 + (l0 >> 5)) * 4096 + d * 32;
    *(uint4*)(vdst)      = *(uint4*)(ov);
    *(uint4*)(vdst + 8)  = *(uint4*)(ov + 8);
    *(uint4*)(vdst + 16) = *(uint4*)(ov + 16);
    *(uint4*)(vdst + 24) = *(uint4*)(ov + 24);
  }
}

// ---------------- Kernel 4: ip projections via split-bf16 MFMA (2-phase dbuf) --
__global__ __launch_bounds__(256) void proj_kernel(
    const unsigned short* __restrict__ Ah, const unsigned short* __restrict__ Al,
    const float* __restrict__ Wk, const float* __restrict__ Wv,
    const float* __restrict__ g_ipk,
    unsigned short* __restrict__ Kb, unsigned short* __restrict__ Vt) {
  // per-buf layout (ushort offsets): Ahs 0, Als 2048, Whs 4096, Wls 8192; buf stride 12288
  __shared__ __align__(16) unsigned short lds_u[24576];   // 48 KB (double-buffered)
  const float* W = blockIdx.z ? Wv : Wk;
  int h = blockIdx.y;
  int m0 = blockIdx.x * 64;
  int tid = threadIdx.x;
  int w = tid >> 6, lane = tid & 63;
  int m = lane & 15, quad = lane >> 4;

  const float* wrow = W + (long)(h * Dh + (tid & 127)) * DIP + ((tid >> 7) << 3);
  const unsigned short* garow_h = Ah + (long)(m0 + lane) * DIP + w * 8;
  const unsigned short* garow_l = Al + (long)(m0 + lane) * DIP + w * 8;

  f32x4 acc[8];
#pragma unroll
  for (int i = 0; i < 8; i++) acc[i] = (f32x4){0.f, 0.f, 0.f, 0.f};

  float4 wa = *(const float4*)(wrow);
  float4 wb = *(const float4*)(wrow + 4);
  float4 wc = *(const float4*)(wrow + 16);
  float4 wd = *(const float4*)(wrow + 20);

  auto stagek = [&](int b, int k0) {
    float cur[16] = {wa.x, wa.y, wa.z, wa.w, wb.x, wb.y, wb.z, wb.w,
                     wc.x, wc.y, wc.z, wc.w, wd.x, wd.y, wd.z, wd.w};
    if (k0 + 32 < DIP) {   // prefetch next K-step's W regs (hidden under compute)
      wa = *(const float4*)(wrow + k0 + 32);
      wb = *(const float4*)(wrow + k0 + 36);
      wc = *(const float4*)(wrow + k0 + 48);
      wd = *(const float4*)(wrow + k0 + 52);
    }
    unsigned short hi[16], lo[16];
#pragma unroll
    for (int i = 0; i < 16; i++) {
      unsigned short hb = f2bf(cur[i]);
      hi[i] = hb;
      lo[i] = f2bf(cur[i] - bf2f(hb));
    }
    unsigned short* AhsB = lds_u + b * 12288;
    unsigned short* AlsB = AhsB + 2048;
    unsigned short* WhsB = AhsB + 4096;
    unsigned short* WlsB = AhsB + 8192;
    __builtin_amdgcn_global_load_lds((gu32*)(garow_h + k0), (lu32*)(AhsB + w * 512), 16, 0, 0);
    __builtin_amdgcn_global_load_lds((gu32*)(garow_l + k0), (lu32*)(AlsB + w * 512), 16, 0, 0);
    *(uint4*)(WhsB + tid * 8) = *(uint4*)(hi);
    *(uint4*)(WlsB + tid * 8) = *(uint4*)(lo);
    *(uint4*)(WhsB + (tid + 256) * 8) = *(uint4*)(hi + 8);
    *(uint4*)(WlsB + (tid + 256) * 8) = *(uint4*)(lo + 8);
  };

  stagek(0, 0);
  __syncthreads();
  int buf = 0;
#pragma unroll 1
  for (int k0 = 0; k0 < DIP; k0 += 32) {
    if (k0 + 32 < DIP) stagek(buf ^ 1, k0 + 32);  // issue next tile before compute
    unsigned short* AhsB = lds_u + buf * 12288;
    unsigned short* AlsB = AhsB + 2048;
    unsigned short* WhsB = AhsB + 4096;
    unsigned short* WlsB = AhsB + 8192;
    bf16x8 ahf = *(const bf16x8*)(AhsB + ((quad << 6) + (w << 4) + m) * 8);
    bf16x8 alf = *(const bf16x8*)(AlsB + ((quad << 6) + (w << 4) + m) * 8);
#pragma unroll
    for (int nt = 0; nt < 8; nt++) {
      bf16x8 bhf = *(const bf16x8*)(WhsB + ((quad << 7) + (nt << 4) + m) * 8);
      bf16x8 blf = *(const bf16x8*)(WlsB + ((quad << 7) + (nt << 4) + m) * 8);
      acc[nt] = __builtin_amdgcn_mfma_f32_16x16x32_bf16(ahf, bhf, acc[nt], 0, 0, 0);
      acc[nt] = __builtin_amdgcn_mfma_f32_16x16x32_bf16(ahf, blf, acc[nt], 0, 0, 0);
      acc[nt] = __builtin_amdgcn_mfma_f32_16x16x32_bf16(alf, bhf, acc[nt], 0, 0, 0);
    }
    __syncthreads();   // drains this iter's loads (hidden under the MFMAs above)
    buf ^= 1;
  }

  if (blockIdx.z == 0) {
    float gkv[8];
#pragma unroll
    for (int nt = 0; nt < 8; nt++) gkv[nt] = g_ipk[nt * 16 + m];
#pragma unroll
    for (int r = 0; r < 4; r++) {
      float ssq = 0.f;
#pragma unroll
      for (int nt = 0; nt < 8; nt++) ssq += acc[nt][r] * acc[nt][r];
      ssq += __shfl_xor(ssq, 1, 16);
      ssq += __shfl_xor(ssq, 2, 16);
      ssq += __shfl_xor(ssq, 4, 16);
      ssq += __shfl_xor(ssq, 8, 16);
      float rstd = rsqrtf(ssq * (1.f / Dh) + EPSF);
      long row = (long)h * LK + LIMG + m0 + w * 16 + quad * 4 + r;
#pragma unroll
      for (int nt = 0; nt < 8; nt++)
        Kb[row * Dh + nt * 16 + m] = f2bf(acc[nt][r] * rstd * gkv[nt]);
    }
  } else {
    // tiled Vt: [h][tile][128 d][32 cols]; rows l0q..l0q+3 are contiguous cols
    int l0q = LIMG + m0 + w * 16 + quad * 4;
    unsigned short* vbase = Vt + ((long)h * 80 + (l0q >> 5)) * 4096 + (l0q & 31);
#pragma unroll
    for (int nt = 0; nt < 8; nt++) {
      ushort4 o;
      o.x = f2bf(acc[nt][0]); o.y = f2bf(acc[nt][1]);
      o.z = f2bf(acc[nt][2]); o.w = f2bf(acc[nt][3]);
      *(ushort4*)(vbase + (nt * 16 + m) * 32) = o;
    }
  }
}

// ---------------- Kernel 5: MFMA flash attention (BQ=128, 2 q-groups/wave) ----
// 4 waves; wave owns 32 q-rows (2 groups of 16) -> each bk/bv LDS load feeds 2
// MFMAs (halves LDS bytes/FLOP). BK=32, dbuf, XCD-clustered grid 384.
// Swapped QK^T softmax (lane owns q-row), defer-max, hoisted stage pointers.
__global__ __launch_bounds__(256, 3) void flash_kernel(
    const float* __restrict__ q_in, const float* __restrict__ g_q,
    const unsigned short* __restrict__ Kb, const unsigned short* __restrict__ Vt,
    float* __restrict__ out) {
  __shared__ __align__(16) unsigned char lds[16384 + 16384 + 10240];  // 42 KB
  unsigned short* Ks = (unsigned short*)lds;            // [2][32][16g] XOR-16 swz
  unsigned short* Vs = (unsigned short*)(lds + 16384);  // [2][128][4g] XOR-(d>>1) swz
  unsigned short* Ps = (unsigned short*)(lds + 32768);  // [4 waves][2 grp][16][40]
  int tid = threadIdx.x;
  int w = tid >> 6, lid = tid & 63;
  int m = lid & 15, quad = lid >> 4;
  int id = blockIdx.x;
  int sidx = id >> 3;
  int h = (id & 7) * 3 + (sidx >> 4);   // XCD (id%8) gets heads 3x..3x+2
  int q0 = (sidx & 15) * 128;

  // ---- Q: two 16-row groups per wave; RMS over 128 dims; -> A-frags ----
  bf16x8 aq[2][4];
#pragma unroll
  for (int g2 = 0; g2 < 2; g2++) {
    float qf[4][8];
    float ssq = 0.f;
    int qrow = q0 + w * 32 + g2 * 16 + m;
    const float* qsrc = q_in + (long)qrow * DM + h * Dh + quad * 8;
#pragma unroll
    for (int ks = 0; ks < 4; ks++) {
      float4 a = *(const float4*)(qsrc + ks * 32);
      float4 b = *(const float4*)(qsrc + ks * 32 + 4);
      qf[ks][0]=a.x; qf[ks][1]=a.y; qf[ks][2]=a.z; qf[ks][3]=a.w;
      qf[ks][4]=b.x; qf[ks][5]=b.y; qf[ks][6]=b.z; qf[ks][7]=b.w;
      ssq += a.x*a.x + a.y*a.y + a.z*a.z + a.w*a.w;
      ssq += b.x*b.x + b.y*b.y + b.z*b.z + b.w*b.w;
    }
    ssq += __shfl_xor(ssq, 16, 64);
    ssq += __shfl_xor(ssq, 32, 64);
    float rstd = rsqrtf(ssq * (1.f / Dh) + EPSF);
    const float* gq = g_q + quad * 8;
#pragma unroll
    for (int ks = 0; ks < 4; ks++) {
      float4 ga = *(const float4*)(gq + ks * 32);
      float4 gb = *(const float4*)(gq + ks * 32 + 4);
      float gg[8] = {ga.x, ga.y, ga.z, ga.w, gb.x, gb.y, gb.z, gb.w};
#pragma unroll
      for (int j = 0; j < 8; j++)
        aq[g2][ks][j] = (short)f2bf(qf[ks][j] * rstd * gg[j]);
    }
  }

  const unsigned short* KbH = Kb + (long)h * LK * Dh;
  const unsigned short* VtH = Vt + (long)h * 80 * 4096;
  unsigned short* Pw0 = Ps + (w * 2 + 0) * 640;
  unsigned short* Pw1 = Ps + (w * 2 + 1) * 640;

  // ---- hoisted per-lane stage pointers (advance 8192 B per tile) ----
  int s0 = w * 128 + lid, s1 = s0 + 64;
  int rK0 = s0 >> 4, cK0 = (s0 & 15) ^ (rK0 & 15);
  int rK1 = s1 >> 4, cK1 = (s1 & 15) ^ (rK1 & 15);
  const unsigned short* pK0 = KbH + (long)rK0 * Dh + cK0 * 8;
  const unsigned short* pK1 = KbH + (long)rK1 * Dh + cK1 * 8;
  int dV0 = s0 >> 2, cV0 = (s0 & 3) ^ ((dV0 >> 1) & 3);
  int dV1 = s1 >> 2, cV1 = (s1 & 3) ^ ((dV1 >> 1) & 3);
  const unsigned short* pV0 = VtH + dV0 * 32 + cV0 * 8;
  const unsigned short* pV1 = VtH + dV1 * 32 + cV1 * 8;

  f32x4 acc0[8], acc1[8];
#pragma unroll
  for (int i = 0; i < 8; i++) {
    acc0[i] = (f32x4){0.f, 0.f, 0.f, 0.f};
    acc1[i] = (f32x4){0.f, 0.f, 0.f, 0.f};
  }
  float mrun0 = -INFINITY, mrun1 = -INFINITY;
  float lrun0 = 0.f, lrun1 = 0.f;

  auto stage = [&](int b) {
    unsigned short* KsB = Ks + b * 4096;
    unsigned short* VsB = Vs + b * 4096;
    __builtin_amdgcn_global_load_lds((gu32*)pK0, (lu32*)(KsB + (w * 128) * 8), 16, 0, 0);
    __builtin_amdgcn_global_load_lds((gu32*)pK1, (lu32*)(KsB + (w * 128 + 64) * 8), 16, 0, 0);
    __builtin_amdgcn_global_load_lds((gu32*)pV0, (lu32*)(VsB + (w * 128) * 8), 16, 0, 0);
    __builtin_amdgcn_global_load_lds((gu32*)pV1, (lu32*)(VsB + (w * 128 + 64) * 8), 16, 0, 0);
    pK0 += 4096; pK1 += 4096;   // next K tile: 32 rows x 128
    pV0 += 4096; pV1 += 4096;   // next V tile: 128 x 32
  };

  stage(0);
  __syncthreads();
  int buf = 0;
#pragma unroll 1
  for (int jt = 0; jt < LK / 32; ++jt) {
    if (jt + 1 < LK / 32) stage(buf ^ 1);  // issue next tile first
    unsigned short* KsB = Ks + buf * 4096;
    unsigned short* VsB = Vs + buf * 4096;

    // ---- S^T = K Q^T, both q-groups share each bk load ----
    f32x4 sc0[2], sc1[2];
    sc0[0] = (f32x4){0.f,0.f,0.f,0.f}; sc0[1] = (f32x4){0.f,0.f,0.f,0.f};
    sc1[0] = (f32x4){0.f,0.f,0.f,0.f}; sc1[1] = (f32x4){0.f,0.f,0.f,0.f};
    __builtin_amdgcn_s_setprio(1);
#pragma unroll
    for (int t = 0; t < 2; t++)
#pragma unroll
      for (int ks = 0; ks < 4; ks++) {
        int rr = t * 16 + m;
        int g = (ks * 4 + quad) ^ m;
        bf16x8 bk = *(const bf16x8*)(KsB + rr * 128 + g * 8);
        sc0[t] = __builtin_amdgcn_mfma_f32_16x16x32_bf16(bk, aq[0][ks], sc0[t], 0, 0, 0);
        sc1[t] = __builtin_amdgcn_mfma_f32_16x16x32_bf16(bk, aq[1][ks], sc1[t], 0, 0, 0);
      }
    __builtin_amdgcn_s_setprio(0);

    // ---- per-lane online softmax, group 0 ----
    float al0 = 1.f, al1 = 1.f;
    int nr0, nr1;
    {
      float pv[8] = {sc0[0][0], sc0[0][1], sc0[0][2], sc0[0][3],
                     sc0[1][0], sc0[1][1], sc0[1][2], sc0[1][3]};
      float tmax = fmaxf(fmaxf(fmaxf(pv[0],pv[1]), fmaxf(pv[2],pv[3])),
                         fmaxf(fmaxf(pv[4],pv[5]), fmaxf(pv[6],pv[7])));
      tmax = fmaxf(tmax, __shfl_xor(tmax, 16, 64));
      tmax = fmaxf(tmax, __shfl_xor(tmax, 32, 64));
      nr0 = __all(tmax <= mrun0 + THRU);
      if (!nr0) {
        float mn = fmaxf(mrun0, tmax);
        al0 = EXP2F((mrun0 - mn) * C2EXP);
        mrun0 = mn;
      }
      float p[8]; unsigned short pb[8];
#pragma unroll
      for (int j = 0; j < 8; j++) {
        p[j] = EXP2F((pv[j] - mrun0) * C2EXP);
        pb[j] = f2bf(p[j]);
      }
      float rs = (p[0]+p[1]) + (p[2]+p[3]) + (p[4]+p[5]) + (p[6]+p[7]);
      rs += __shfl_xor(rs, 16, 64);
      rs += __shfl_xor(rs, 32, 64);
      lrun0 = lrun0 * al0 + rs;
      uint2 pk0, pk1;
      pk0.x = (unsigned)pb[0] | ((unsigned)pb[1] << 16);
      pk0.y = (unsigned)pb[2] | ((unsigned)pb[3] << 16);
      pk1.x = (unsigned)pb[4] | ((unsigned)pb[5] << 16);
      pk1.y = (unsigned)pb[6] | ((unsigned)pb[7] << 16);
      *(uint2*)(Pw0 + m * 40 + quad * 4) = pk0;
      *(uint2*)(Pw0 + m * 40 + 16 + quad * 4) = pk1;
    }
    // ---- group 1 ----
    {
      float pv[8] = {sc1[0][0], sc1[0][1], sc1[0][2], sc1[0][3],
                     sc1[1][0], sc1[1][1], sc1[1][2], sc1[1][3]};
      float tmax = fmaxf(fmaxf(fmaxf(pv[0],pv[1]), fmaxf(pv[2],pv[3])),
                         fmaxf(fmaxf(pv[4],pv[5]), fmaxf(pv[6],pv[7])));
      tmax = fmaxf(tmax, __shfl_xor(tmax, 16, 64));
      tmax = fmaxf(tmax, __shfl_xor(tmax, 32, 64));
      nr1 = __all(tmax <= mrun1 + THRU);
      if (!nr1) {
        float mn = fmaxf(mrun1, tmax);
        al1 = EXP2F((mrun1 - mn) * C2EXP);
        mrun1 = mn;
      }
      float p[8]; unsigned short pb[8];
#pragma unroll
      for (int j = 0; j < 8; j++) {
        p[j] = EXP2F((pv[j] - mrun1) * C2EXP);
        pb[j] = f2bf(p[j]);
      }
      float rs = (p[0]+p[1]) + (p[2]+p[3]) + (p[4]+p[5]) + (p[6]+p[7]);
      rs += __shfl_xor(rs, 16, 64);
      rs += __shfl_xor(rs, 32, 64);
      lrun1 = lrun1 * al1 + rs;
      uint2 pk0, pk1;
      pk0.x = (unsigned)pb[0] | ((unsigned)pb[1] << 16);
      pk0.y = (unsigned)pb[2] | ((unsigned)pb[3] << 16);
      pk1.x = (unsigned)pb[4] | ((unsigned)pb[5] << 16);
      pk1.y = (unsigned)pb[6] | ((unsigned)pb[7] << 16);
      *(uint2*)(Pw1 + m * 40 + quad * 4) = pk0;
      *(uint2*)(Pw1 + m * 40 + 16 + quad * 4) = pk1;
    }
    bf16x8 ap0 = *(const bf16x8*)(Pw0 + m * 40 + quad * 8);
    bf16x8 ap1 = *(const bf16x8*)(Pw1 + m * 40 + quad * 8);

    if (!nr0) {   // wave-uniform rescale, group 0
      float alr[4];
#pragma unroll
      for (int r = 0; r < 4; r++) alr[r] = __shfl(al0, quad * 4 + r, 16);
#pragma unroll
      for (int dt = 0; dt < 8; dt++) {
        acc0[dt][0] *= alr[0]; acc0[dt][1] *= alr[1];
        acc0[dt][2] *= alr[2]; acc0[dt][3] *= alr[3];
      }
    }
    if (!nr1) {   // group 1
      float alr[4];
#pragma unroll
      for (int r = 0; r < 4; r++) alr[r] = __shfl(al1, quad * 4 + r, 16);
#pragma unroll
      for (int dt = 0; dt < 8; dt++) {
        acc1[dt][0] *= alr[0]; acc1[dt][1] *= alr[1];
        acc1[dt][2] *= alr[2]; acc1[dt][3] *= alr[3];
      }
    }

    // ---- PV: each bv load feeds both groups ----
    __builtin_amdgcn_s_setprio(1);
#pragma unroll
    for (int dt = 0; dt < 8; dt++) {
      bf16x8 bv = *(const bf16x8*)(VsB + ((dt * 16 + m) * 4 + (quad ^ ((m >> 1) & 3))) * 8);
      acc0[dt] = __builtin_amdgcn_mfma_f32_16x16x32_bf16(ap0, bv, acc0[dt], 0, 0, 0);
      acc1[dt] = __builtin_amdgcn_mfma_f32_16x16x32_bf16(ap1, bv, acc1[dt], 0, 0, 0);
    }
    __builtin_amdgcn_s_setprio(0);
    __syncthreads();   // drains this tile's prefetch (hidden under compute above)
    buf ^= 1;
  }

  // ---- epilogue ----
  {
    float inv = 1.f / lrun0;
    float ilr[4];
#pragma unroll
    for (int r = 0; r < 4; r++) ilr[r] = __shfl(inv, quad * 4 + r, 16);
#pragma unroll
    for (int dt = 0; dt < 8; dt++)
#pragma unroll
      for (int r = 0; r < 4; r++)
        out[(long)(q0 + w * 32 + quad * 4 + r) * DM + h * Dh + dt * 16 + m] =
            acc0[dt][r] * ilr[r];
  }
  {
    float inv = 1.f / lrun1;
    float ilr[4];
#pragma unroll
    for (int r = 0; r < 4; r++) ilr[r] = __shfl(inv, quad * 4 + r, 16);
#pragma unroll
    for (int dt = 0; dt < 8; dt++)
#pragma unroll
      for (int r = 0; r < 4; r++)
        out[(long)(q0 + w * 32 + 16 + quad * 4 + r) * DM + h * Dh + dt * 16 + m] =
            acc1[dt][r] * ilr[r];
  }
}

// ---------------- launch ----------------
extern "C" void kernel_launch(void* const* d_in, const int* in_sizes, int n_in,
                              void* d_out, int out_size, void* d_ws, size_t ws_size,
                              hipStream_t stream) {
  const float* ip_hidden = (const float*)d_in[0];
  const float* img_q     = (const float*)d_in[1];
  const float* img_k     = (const float*)d_in[2];
  const float* img_v     = (const float*)d_in[3];
  const float* t_emb     = (const float*)d_in[4];
  const float* w_ada     = (const float*)d_in[5];
  const float* b_ada     = (const float*)d_in[6];
  const float* w_k_ip    = (const float*)d_in[7];
  const float* w_v_ip    = (const float*)d_in[8];
  const float* g_q       = (const float*)d_in[9];
  const float* g_k       = (const float*)d_in[10];
  const float* g_ipk     = (const float*)d_in[11];

  char* base = (char*)d_ws;
  float* e = (float*)base;
  unsigned short* ipnh = (unsigned short*)(base + 16384);
  unsigned short* ipnl = (unsigned short*)(base + 1327104);
  unsigned short* Kb   = (unsigned short*)(base + 2637824);
  unsigned short* Vt   = Kb + (size_t)H * LK * Dh;
  float* out = (float*)d_out;

  ada_kernel<<<2 * DIP, 256, 0, stream>>>(t_emb, w_ada, b_ada, e);
  adaln_kernel<<<LIP, 256, 0, stream>>>(ip_hidden, e, ipnh, ipnl);
  prep_kernel<<<dim3(LIMG / 32, H), 256, 0, stream>>>(img_k, img_v, g_k, Kb, Vt);
  proj_kernel<<<dim3(LIP / 64, H, 2), 256, 0, stream>>>(ipnh, ipnl, w_k_ip, w_v_ip,
                                                        g_ipk, Kb, Vt);
  flash_kernel<<<dim3(384), 256, 0, stream>>>(img_q, g_q, Kb, Vt, out);
}

// Round 6
// 384.509 us; speedup vs baseline: 1.0902x; 1.0902x over previous
//
#include <hip/hip_runtime.h>
#include <math.h>

#define H    24
#define Dh   128
#define LIMG 2048
#define LIP  512
#define DM   3072
#define DIP  1280
#define LK   2560
#define EPSF 1e-6f
#define SM_SCALE 0.08838834764831845f  // 1/sqrt(128)
#define C2EXP 0.12751930f              // SM_SCALE * log2(e)
#define THRU 90.50967f                 // 8 / SM_SCALE (defer-max threshold, unscaled)

#define EXP2F(x) __builtin_exp2f(x)    // lowers to v_exp_f32 (HW is base-2)

typedef __attribute__((ext_vector_type(8))) short bf16x8;
typedef __attribute__((ext_vector_type(4))) float f32x4;

typedef const unsigned int __attribute__((address_space(1))) gu32;
typedef unsigned int __attribute__((address_space(3))) lu32;

static __device__ __forceinline__ unsigned short f2bf(float x) {
  union { float f; unsigned u; } v; v.f = x;
  unsigned r = v.u + 0x7fffu + ((v.u >> 16) & 1u);  // RNE
  return (unsigned short)(r >> 16);
}

static __device__ __forceinline__ float bf2f(unsigned short b) {
  union { unsigned u; float f; } v; v.u = ((unsigned)b) << 16;
  return v.f;
}

// ---------------- Kernel 1: e = silu(t_emb) @ w_ada^T + b_ada ----------------
__global__ __launch_bounds__(256) void ada_kernel(
    const float* __restrict__ t_emb, const float* __restrict__ w_ada,
    const float* __restrict__ b_ada, float* __restrict__ e) {
  int j = blockIdx.x;
  int tid = threadIdx.x;
  const float* wrow = w_ada + (long)j * DIP;
  float acc = 0.f;
  for (int k = tid; k < DIP; k += 256) {
    float t = t_emb[k];
    acc += (t / (1.f + expf(-t))) * wrow[k];
  }
#pragma unroll
  for (int m = 1; m < 64; m <<= 1) acc += __shfl_xor(acc, m, 64);
  __shared__ float red[4];
  if ((tid & 63) == 0) red[tid >> 6] = acc;
  __syncthreads();
  if (tid == 0) e[j] = red[0] + red[1] + red[2] + red[3] + b_ada[j];
}

// ---------------- Kernel 2: AdaLayerNorm -> ip_norm as bf16 hi/lo planes ----
__global__ __launch_bounds__(256) void adaln_kernel(
    const float* __restrict__ x, const float* __restrict__ e,
    unsigned short* __restrict__ ipnh, unsigned short* __restrict__ ipnl) {
  int r = blockIdx.x;
  int tid = threadIdx.x;
  const float* xr = x + (long)r * DIP;
  float v[5];
  float s = 0.f, ss = 0.f;
#pragma unroll
  for (int i = 0; i < 5; i++) {
    v[i] = xr[tid + i * 256];
    s += v[i];
    ss += v[i] * v[i];
  }
#pragma unroll
  for (int m = 1; m < 64; m <<= 1) {
    s += __shfl_xor(s, m, 64);
    ss += __shfl_xor(ss, m, 64);
  }
  __shared__ float rs_[4], rss_[4];
  if ((tid & 63) == 0) { rs_[tid >> 6] = s; rss_[tid >> 6] = ss; }
  __syncthreads();
  s = rs_[0] + rs_[1] + rs_[2] + rs_[3];
  ss = rss_[0] + rss_[1] + rss_[2] + rss_[3];
  float mu = s * (1.f / DIP);
  float var = ss * (1.f / DIP) - mu * mu;
  float rstd = rsqrtf(var + EPSF);
  unsigned short* oh = ipnh + (long)r * DIP;
  unsigned short* ol = ipnl + (long)r * DIP;
#pragma unroll
  for (int i = 0; i < 5; i++) {
    int c = tid + i * 256;
    float o = (v[i] - mu) * rstd * (1.f + e[DIP + c]) + e[c];
    unsigned short hb = f2bf(o);
    oh[c] = hb;
    ol[c] = f2bf(o - bf2f(hb));
  }
}

// ---------------- Kernel 3: img K (RMS) -> Kb bf16, img V -> Vt bf16 (tiled) --
// Kb[H][LK][128]; Vt tiled: [H][LK/32 tiles][128 d][32 cols] (8 KB contiguous tiles).
__global__ __launch_bounds__(256) void prep_kernel(
    const float* __restrict__ k_in, const float* __restrict__ v_in,
    const float* __restrict__ g_k,
    unsigned short* __restrict__ Kb, unsigned short* __restrict__ Vt) {
  __shared__ unsigned short Vls[128][33];
  int h = blockIdx.y, l0 = blockIdx.x * 32;
  int tid = threadIdx.x;
  int r = tid >> 3, c = tid & 7;   // 8 threads/row, 16 elems each
  const float* ksrc = k_in + (long)(l0 + r) * DM + h * Dh + c * 16;
  const float* vsrc = v_in + (long)(l0 + r) * DM + h * Dh + c * 16;
  float kv[16], vv[16];
  float ssq = 0.f;
#pragma unroll
  for (int i = 0; i < 4; i++) {
    float4 a = *(const float4*)(ksrc + i * 4);
    float4 b = *(const float4*)(vsrc + i * 4);
    kv[i*4+0]=a.x; kv[i*4+1]=a.y; kv[i*4+2]=a.z; kv[i*4+3]=a.w;
    vv[i*4+0]=b.x; vv[i*4+1]=b.y; vv[i*4+2]=b.z; vv[i*4+3]=b.w;
    ssq += a.x*a.x + a.y*a.y + a.z*a.z + a.w*a.w;
  }
  ssq += __shfl_xor(ssq, 1, 8);
  ssq += __shfl_xor(ssq, 2, 8);
  ssq += __shfl_xor(ssq, 4, 8);
  float rstd = rsqrtf(ssq * (1.f / Dh) + EPSF);
  unsigned short kb[16];
#pragma unroll
  for (int i = 0; i < 16; i++) kb[i] = f2bf(kv[i] * rstd * g_k[c * 16 + i]);
  unsigned short* kdst = Kb + ((long)h * LK + l0 + r) * Dh + c * 16;
  *(uint4*)(kdst) = *(uint4*)(kb);
  *(uint4*)(kdst + 8) = *(uint4*)(kb + 8);
  // transpose V through LDS
#pragma unroll
  for (int i = 0; i < 16; i++) Vls[c * 16 + i][r] = f2bf(vv[i]);
  __syncthreads();
  if (tid < 128) {   // one thread per d-row: 64B store, tile-contiguous dest
    int d = tid;
    unsigned short ov[32];
#pragma unroll
    for (int j = 0; j < 32; j++) ov[j] = Vls[d][j];
    unsigned short* vdst = Vt + ((long)h * 80 + (l0 >> 5)) * 4096 + d * 32;
    *(uint4*)(vdst)      = *(uint4*)(ov);
    *(uint4*)(vdst + 8)  = *(uint4*)(ov + 8);
    *(uint4*)(vdst + 16) = *(uint4*)(ov + 16);
    *(uint4*)(vdst + 24) = *(uint4*)(ov + 24);
  }
}

// ---------------- Kernel 4: ip projections via split-bf16 MFMA (2-phase dbuf) --
__global__ __launch_bounds__(256) void proj_kernel(
    const unsigned short* __restrict__ Ah, const unsigned short* __restrict__ Al,
    const float* __restrict__ Wk, const float* __restrict__ Wv,
    const float* __restrict__ g_ipk,
    unsigned short* __restrict__ Kb, unsigned short* __restrict__ Vt) {
  // per-buf layout (ushort offsets): Ahs 0, Als 2048, Whs 4096, Wls 8192; buf stride 12288
  __shared__ __align__(16) unsigned short lds_u[24576];   // 48 KB (double-buffered)
  const float* W = blockIdx.z ? Wv : Wk;
  int h = blockIdx.y;
  int m0 = blockIdx.x * 64;
  int tid = threadIdx.x;
  int w = tid >> 6, lane = tid & 63;
  int m = lane & 15, quad = lane >> 4;

  const float* wrow = W + (long)(h * Dh + (tid & 127)) * DIP + ((tid >> 7) << 3);
  const unsigned short* garow_h = Ah + (long)(m0 + lane) * DIP + w * 8;
  const unsigned short* garow_l = Al + (long)(m0 + lane) * DIP + w * 8;

  f32x4 acc[8];
#pragma unroll
  for (int i = 0; i < 8; i++) acc[i] = (f32x4){0.f, 0.f, 0.f, 0.f};

  float4 wa = *(const float4*)(wrow);
  float4 wb = *(const float4*)(wrow + 4);
  float4 wc = *(const float4*)(wrow + 16);
  float4 wd = *(const float4*)(wrow + 20);

  auto stagek = [&](int b, int k0) {
    float cur[16] = {wa.x, wa.y, wa.z, wa.w, wb.x, wb.y, wb.z, wb.w,
                     wc.x, wc.y, wc.z, wc.w, wd.x, wd.y, wd.z, wd.w};
    if (k0 + 32 < DIP) {   // prefetch next K-step's W regs (hidden under compute)
      wa = *(const float4*)(wrow + k0 + 32);
      wb = *(const float4*)(wrow + k0 + 36);
      wc = *(const float4*)(wrow + k0 + 48);
      wd = *(const float4*)(wrow + k0 + 52);
    }
    unsigned short hi[16], lo[16];
#pragma unroll
    for (int i = 0; i < 16; i++) {
      unsigned short hb = f2bf(cur[i]);
      hi[i] = hb;
      lo[i] = f2bf(cur[i] - bf2f(hb));
    }
    unsigned short* AhsB = lds_u + b * 12288;
    unsigned short* AlsB = AhsB + 2048;
    unsigned short* WhsB = AhsB + 4096;
    unsigned short* WlsB = AhsB + 8192;
    __builtin_amdgcn_global_load_lds((gu32*)(garow_h + k0), (lu32*)(AhsB + w * 512), 16, 0, 0);
    __builtin_amdgcn_global_load_lds((gu32*)(garow_l + k0), (lu32*)(AlsB + w * 512), 16, 0, 0);
    *(uint4*)(WhsB + tid * 8) = *(uint4*)(hi);
    *(uint4*)(WlsB + tid * 8) = *(uint4*)(lo);
    *(uint4*)(WhsB + (tid + 256) * 8) = *(uint4*)(hi + 8);
    *(uint4*)(WlsB + (tid + 256) * 8) = *(uint4*)(lo + 8);
  };

  stagek(0, 0);
  __syncthreads();
  int buf = 0;
#pragma unroll 1
  for (int k0 = 0; k0 < DIP; k0 += 32) {
    if (k0 + 32 < DIP) stagek(buf ^ 1, k0 + 32);  // issue next tile before compute
    unsigned short* AhsB = lds_u + buf * 12288;
    unsigned short* AlsB = AhsB + 2048;
    unsigned short* WhsB = AhsB + 4096;
    unsigned short* WlsB = AhsB + 8192;
    bf16x8 ahf = *(const bf16x8*)(AhsB + ((quad << 6) + (w << 4) + m) * 8);
    bf16x8 alf = *(const bf16x8*)(AlsB + ((quad << 6) + (w << 4) + m) * 8);
#pragma unroll
    for (int nt = 0; nt < 8; nt++) {
      bf16x8 bhf = *(const bf16x8*)(WhsB + ((quad << 7) + (nt << 4) + m) * 8);
      bf16x8 blf = *(const bf16x8*)(WlsB + ((quad << 7) + (nt << 4) + m) * 8);
      acc[nt] = __builtin_amdgcn_mfma_f32_16x16x32_bf16(ahf, bhf, acc[nt], 0, 0, 0);
      acc[nt] = __builtin_amdgcn_mfma_f32_16x16x32_bf16(ahf, blf, acc[nt], 0, 0, 0);
      acc[nt] = __builtin_amdgcn_mfma_f32_16x16x32_bf16(alf, bhf, acc[nt], 0, 0, 0);
    }
    __syncthreads();   // drains this iter's loads (hidden under the MFMAs above)
    buf ^= 1;
  }

  if (blockIdx.z == 0) {
    float gkv[8];
#pragma unroll
    for (int nt = 0; nt < 8; nt++) gkv[nt] = g_ipk[nt * 16 + m];
#pragma unroll
    for (int r = 0; r < 4; r++) {
      float ssq = 0.f;
#pragma unroll
      for (int nt = 0; nt < 8; nt++) ssq += acc[nt][r] * acc[nt][r];
      ssq += __shfl_xor(ssq, 1, 16);
      ssq += __shfl_xor(ssq, 2, 16);
      ssq += __shfl_xor(ssq, 4, 16);
      ssq += __shfl_xor(ssq, 8, 16);
      float rstd = rsqrtf(ssq * (1.f / Dh) + EPSF);
      long row = (long)h * LK + LIMG + m0 + w * 16 + quad * 4 + r;
#pragma unroll
      for (int nt = 0; nt < 8; nt++)
        Kb[row * Dh + nt * 16 + m] = f2bf(acc[nt][r] * rstd * gkv[nt]);
    }
  } else {
    // tiled Vt: [h][tile][128 d][32 cols]; rows l0q..l0q+3 are contiguous cols
    int l0q = LIMG + m0 + w * 16 + quad * 4;
    unsigned short* vbase = Vt + ((long)h * 80 + (l0q >> 5)) * 4096 + (l0q & 31);
#pragma unroll
    for (int nt = 0; nt < 8; nt++) {
      ushort4 o;
      o.x = f2bf(acc[nt][0]); o.y = f2bf(acc[nt][1]);
      o.z = f2bf(acc[nt][2]); o.w = f2bf(acc[nt][3]);
      *(ushort4*)(vbase + (nt * 16 + m) * 32) = o;
    }
  }
}

// ---------------- Kernel 5: MFMA flash attention ----------------
// Round-4 geometry (BQ=64, grid 768, 3 blocks/CU) + hoisted stage pointers,
// fixed Vs swizzle, tiled Vt, no fence, and K-loop unrolled x2 (static buf ->
// LDS addresses loop-invariant).
__global__ __launch_bounds__(256, 4) void flash_kernel(
    const float* __restrict__ q_in, const float* __restrict__ g_q,
    const unsigned short* __restrict__ Kb, const unsigned short* __restrict__ Vt,
    float* __restrict__ out) {
  __shared__ __align__(16) unsigned char lds[16384 + 16384 + 5120];  // 37.9 KB
  unsigned short* Ks = (unsigned short*)lds;            // [2][32][16g] XOR-16 swz
  unsigned short* Vs = (unsigned short*)(lds + 16384);  // [2][128][4g] XOR-(d>>1) swz
  unsigned short* Ps = (unsigned short*)(lds + 32768);  // [4 waves][16][40]
  int tid = threadIdx.x;
  int w = tid >> 6, lid = tid & 63;
  int m = lid & 15, quad = lid >> 4;
  int id = blockIdx.x;
  int sidx = id >> 3;
  int h = (id & 7) * 3 + (sidx >> 5);   // XCD (id%8) gets heads 3x..3x+2
  int q0 = (sidx & 31) * 64;
  int qrow = q0 + w * 16 + m;

  // ---- Q: load fp32, RMS over 128 (quad lanes hold disjoint d), g_q, -> A-frags ----
  bf16x8 aq[4];
  {
    float qf[4][8];
    float ssq = 0.f;
    const float* qsrc = q_in + (long)qrow * DM + h * Dh + quad * 8;
#pragma unroll
    for (int ks = 0; ks < 4; ks++) {
      float4 a = *(const float4*)(qsrc + ks * 32);
      float4 b = *(const float4*)(qsrc + ks * 32 + 4);
      qf[ks][0]=a.x; qf[ks][1]=a.y; qf[ks][2]=a.z; qf[ks][3]=a.w;
      qf[ks][4]=b.x; qf[ks][5]=b.y; qf[ks][6]=b.z; qf[ks][7]=b.w;
      ssq += a.x*a.x + a.y*a.y + a.z*a.z + a.w*a.w;
      ssq += b.x*b.x + b.y*b.y + b.z*b.z + b.w*b.w;
    }
    ssq += __shfl_xor(ssq, 16, 64);
    ssq += __shfl_xor(ssq, 32, 64);
    float rstd = rsqrtf(ssq * (1.f / Dh) + EPSF);
    const float* gq = g_q + quad * 8;
#pragma unroll
    for (int ks = 0; ks < 4; ks++) {
      float4 ga = *(const float4*)(gq + ks * 32);
      float4 gb = *(const float4*)(gq + ks * 32 + 4);
      float gg[8] = {ga.x, ga.y, ga.z, ga.w, gb.x, gb.y, gb.z, gb.w};
#pragma unroll
      for (int j = 0; j < 8; j++)
        aq[ks][j] = (short)f2bf(qf[ks][j] * rstd * gg[j]);
    }
  }

  const unsigned short* KbH = Kb + (long)h * LK * Dh;
  const unsigned short* VtH = Vt + (long)h * 80 * 4096;
  unsigned short* Pw = Ps + w * 640;

  f32x4 acc_o[8];
#pragma unroll
  for (int i = 0; i < 8; i++) acc_o[i] = (f32x4){0.f, 0.f, 0.f, 0.f};
  float mrun = -INFINITY;   // per-lane: q-row = m (all quads redundant)
  float lrun = 0.f;

  // ---- hoisted per-lane stage pointers (advance 8192 B per tile) ----
  int s0 = w * 128 + lid, s1 = s0 + 64;
  int rK0 = s0 >> 4, cK0 = (s0 & 15) ^ (rK0 & 15);
  int rK1 = s1 >> 4, cK1 = (s1 & 15) ^ (rK1 & 15);
  const unsigned short* pK0 = KbH + (long)rK0 * Dh + cK0 * 8;
  const unsigned short* pK1 = KbH + (long)rK1 * Dh + cK1 * 8;
  int dV0 = s0 >> 2, cV0 = (s0 & 3) ^ ((dV0 >> 1) & 3);
  int dV1 = s1 >> 2, cV1 = (s1 & 3) ^ ((dV1 >> 1) & 3);
  const unsigned short* pV0 = VtH + dV0 * 32 + cV0 * 8;
  const unsigned short* pV1 = VtH + dV1 * 32 + cV1 * 8;

  auto stage = [&](int b) {
    unsigned short* KsB = Ks + b * 4096;
    unsigned short* VsB = Vs + b * 4096;
    __builtin_amdgcn_global_load_lds((gu32*)pK0, (lu32*)(KsB + (w * 128) * 8), 16, 0, 0);
    __builtin_amdgcn_global_load_lds((gu32*)pK1, (lu32*)(KsB + (w * 128 + 64) * 8), 16, 0, 0);
    __builtin_amdgcn_global_load_lds((gu32*)pV0, (lu32*)(VsB + (w * 128) * 8), 16, 0, 0);
    __builtin_amdgcn_global_load_lds((gu32*)pV1, (lu32*)(VsB + (w * 128 + 64) * 8), 16, 0, 0);
    pK0 += 4096; pK1 += 4096;   // next K tile: 32 rows x 128
    pV0 += 4096; pV1 += 4096;   // next V tile: 128 x 32
  };

  auto compute = [&](const unsigned short* KsB, const unsigned short* VsB) {
    // ---- S^T = K Q^T : lane (m,quad) -> q=m, k = t*16 + quad*4 + r ----
    f32x4 sc[2];
    sc[0] = (f32x4){0.f, 0.f, 0.f, 0.f};
    sc[1] = (f32x4){0.f, 0.f, 0.f, 0.f};
    __builtin_amdgcn_s_setprio(1);
#pragma unroll
    for (int t = 0; t < 2; t++)
#pragma unroll
      for (int ks = 0; ks < 4; ks++) {
        int rr = t * 16 + m;
        int g = (ks * 4 + quad) ^ m;
        bf16x8 bk = *(const bf16x8*)(KsB + rr * 128 + g * 8);
        sc[t] = __builtin_amdgcn_mfma_f32_16x16x32_bf16(bk, aq[ks], sc[t], 0, 0, 0);
      }
    __builtin_amdgcn_s_setprio(0);

    // ---- per-lane online softmax (unscaled max domain, exp2 folding) ----
    float pv[8] = {sc[0][0], sc[0][1], sc[0][2], sc[0][3],
                   sc[1][0], sc[1][1], sc[1][2], sc[1][3]};
    float t0 = fmaxf(fmaxf(pv[0], pv[1]), fmaxf(pv[2], pv[3]));
    float t1 = fmaxf(fmaxf(pv[4], pv[5]), fmaxf(pv[6], pv[7]));
    float tmax = fmaxf(t0, t1);
    tmax = fmaxf(tmax, __shfl_xor(tmax, 16, 64));
    tmax = fmaxf(tmax, __shfl_xor(tmax, 32, 64));
    int noresc = __all(tmax <= mrun + THRU);   // defer-max (THR=8 scaled)
    float al = 1.f;
    if (!noresc) {
      float mnew = fmaxf(mrun, tmax);
      al = EXP2F((mrun - mnew) * C2EXP);
      mrun = mnew;
    }
    float p[8];
    unsigned short pb[8];
#pragma unroll
    for (int j = 0; j < 8; j++) {
      p[j] = EXP2F((pv[j] - mrun) * C2EXP);
      pb[j] = f2bf(p[j]);
    }
    float rsum = (p[0] + p[1]) + (p[2] + p[3]) + (p[4] + p[5]) + (p[6] + p[7]);
    rsum += __shfl_xor(rsum, 16, 64);
    rsum += __shfl_xor(rsum, 32, 64);
    lrun = lrun * al + rsum;

    // ---- P^T -> LDS (packed b64 writes), read back as PV A-fragment ----
    uint2 pk0, pk1;
    pk0.x = (unsigned)pb[0] | ((unsigned)pb[1] << 16);
    pk0.y = (unsigned)pb[2] | ((unsigned)pb[3] << 16);
    pk1.x = (unsigned)pb[4] | ((unsigned)pb[5] << 16);
    pk1.y = (unsigned)pb[6] | ((unsigned)pb[7] << 16);
    *(uint2*)(Pw + m * 40 + quad * 4) = pk0;
    *(uint2*)(Pw + m * 40 + 16 + quad * 4) = pk1;
    bf16x8 ap = *(const bf16x8*)(Pw + m * 40 + quad * 8);

    if (!noresc) {   // wave-uniform branch
      float alr[4];
#pragma unroll
      for (int r = 0; r < 4; r++) alr[r] = __shfl(al, quad * 4 + r, 16);
#pragma unroll
      for (int dt = 0; dt < 8; dt++) {
        acc_o[dt][0] *= alr[0]; acc_o[dt][1] *= alr[1];
        acc_o[dt][2] *= alr[2]; acc_o[dt][3] *= alr[3];
      }
    }

    __builtin_amdgcn_s_setprio(1);
#pragma unroll
    for (int dt = 0; dt < 8; dt++) {
      bf16x8 bv = *(const bf16x8*)(VsB + ((dt * 16 + m) * 4 + (quad ^ ((m >> 1) & 3))) * 8);
      acc_o[dt] = __builtin_amdgcn_mfma_f32_16x16x32_bf16(ap, bv, acc_o[dt], 0, 0, 0);
    }
    __builtin_amdgcn_s_setprio(0);
  };

  stage(0);
  __syncthreads();
#pragma unroll 1
  for (int jt = 0; jt < LK / 32; jt += 2) {
    stage(1);                         // prefetch odd tile
    compute(Ks, Vs);                  // even tile (buf 0, static)
    __syncthreads();                  // drains buf-1 prefetch
    if (jt + 2 < LK / 32) stage(0);   // prefetch next even tile
    compute(Ks + 4096, Vs + 4096);    // odd tile (buf 1, static)
    __syncthreads();                  // drains buf-0 prefetch
  }

  // ---- epilogue ----
  float inv = 1.f / lrun;
  float ilr[4];
#pragma unroll
  for (int r = 0; r < 4; r++) ilr[r] = __shfl(inv, quad * 4 + r, 16);
#pragma unroll
  for (int dt = 0; dt < 8; dt++)
#pragma unroll
    for (int r = 0; r < 4; r++)
      out[(long)(q0 + w * 16 + quad * 4 + r) * DM + h * Dh + dt * 16 + m] =
          acc_o[dt][r] * ilr[r];
}

// ---------------- launch ----------------
extern "C" void kernel_launch(void* const* d_in, const int* in_sizes, int n_in,
                              void* d_out, int out_size, void* d_ws, size_t ws_size,
                              hipStream_t stream) {
  const float* ip_hidden = (const float*)d_in[0];
  const float* img_q     = (const float*)d_in[1];
  const float* img_k     = (const float*)d_in[2];
  const float* img_v     = (const float*)d_in[3];
  const float* t_emb     = (const float*)d_in[4];
  const float* w_ada     = (const float*)d_in[5];
  const float* b_ada     = (const float*)d_in[6];
  const float* w_k_ip    = (const float*)d_in[7];
  const float* w_v_ip    = (const float*)d_in[8];
  const float* g_q       = (const float*)d_in[9];
  const float* g_k       = (const float*)d_in[10];
  const float* g_ipk     = (const float*)d_in[11];

  char* base = (char*)d_ws;
  float* e = (float*)base;
  unsigned short* ipnh = (unsigned short*)(base + 16384);
  unsigned short* ipnl = (unsigned short*)(base + 1327104);
  unsigned short* Kb   = (unsigned short*)(base + 2637824);
  unsigned short* Vt   = Kb + (size_t)H * LK * Dh;
  float* out = (float*)d_out;

  ada_kernel<<<2 * DIP, 256, 0, stream>>>(t_emb, w_ada, b_ada, e);
  adaln_kernel<<<LIP, 256, 0, stream>>>(ip_hidden, e, ipnh, ipnl);
  prep_kernel<<<dim3(LIMG / 32, H), 256, 0, stream>>>(img_k, img_v, g_k, Kb, Vt);
  proj_kernel<<<dim3(LIP / 64, H, 2), 256, 0, stream>>>(ipnh, ipnl, w_k_ip, w_v_ip,
                                                        g_ipk, Kb, Vt);
  flash_kernel<<<dim3(768), 256, 0, stream>>>(img_q, g_q, Kb, Vt, out);
}

// Round 7
// 368.393 us; speedup vs baseline: 1.1379x; 1.0437x over previous
//
#include <hip/hip_runtime.h>
#include <math.h>

#define H    24
#define Dh   128
#define LIMG 2048
#define LIP  512
#define DM   3072
#define DIP  1280
#define LK   2560
#define EPSF 1e-6f
#define SM_SCALE 0.08838834764831845f  // 1/sqrt(128)
#define C2EXP 0.12751930f              // SM_SCALE * log2(e)
#define THRU 90.50967f                 // 8 / SM_SCALE (defer-max threshold, unscaled)

#define EXP2F(x) __builtin_exp2f(x)    // lowers to v_exp_f32 (HW is base-2)

typedef __attribute__((ext_vector_type(8))) short bf16x8;
typedef __attribute__((ext_vector_type(4))) float f32x4;

typedef const unsigned int __attribute__((address_space(1))) gu32;
typedef unsigned int __attribute__((address_space(3))) lu32;

static __device__ __forceinline__ unsigned short f2bf(float x) {
  union { float f; unsigned u; } v; v.f = x;
  unsigned r = v.u + 0x7fffu + ((v.u >> 16) & 1u);  // RNE
  return (unsigned short)(r >> 16);
}

static __device__ __forceinline__ float bf2f(unsigned short b) {
  union { unsigned u; float f; } v; v.u = ((unsigned)b) << 16;
  return v.f;
}

// v_cvt_pk_bf16_f32: RNE-rounds two f32 into one packed dword (lo=a, hi=b).
static __device__ __forceinline__ unsigned cvt_pk_bf16(float a, float b) {
  unsigned r;
  asm("v_cvt_pk_bf16_f32 %0, %1, %2" : "=v"(r) : "v"(a), "v"(b));
  return r;
}

// ---------------- Kernel 1: e = silu(t_emb) @ w_ada^T + b_ada ----------------
__global__ __launch_bounds__(256) void ada_kernel(
    const float* __restrict__ t_emb, const float* __restrict__ w_ada,
    const float* __restrict__ b_ada, float* __restrict__ e) {
  int j = blockIdx.x;
  int tid = threadIdx.x;
  const float* wrow = w_ada + (long)j * DIP;
  float acc = 0.f;
  for (int k = tid; k < DIP; k += 256) {
    float t = t_emb[k];
    acc += (t / (1.f + expf(-t))) * wrow[k];
  }
#pragma unroll
  for (int m = 1; m < 64; m <<= 1) acc += __shfl_xor(acc, m, 64);
  __shared__ float red[4];
  if ((tid & 63) == 0) red[tid >> 6] = acc;
  __syncthreads();
  if (tid == 0) e[j] = red[0] + red[1] + red[2] + red[3] + b_ada[j];
}

// ---------------- Kernel 2: AdaLayerNorm -> ip_norm as bf16 hi/lo planes ----
__global__ __launch_bounds__(256) void adaln_kernel(
    const float* __restrict__ x, const float* __restrict__ e,
    unsigned short* __restrict__ ipnh, unsigned short* __restrict__ ipnl) {
  int r = blockIdx.x;
  int tid = threadIdx.x;
  const float* xr = x + (long)r * DIP;
  float v[5];
  float s = 0.f, ss = 0.f;
#pragma unroll
  for (int i = 0; i < 5; i++) {
    v[i] = xr[tid + i * 256];
    s += v[i];
    ss += v[i] * v[i];
  }
#pragma unroll
  for (int m = 1; m < 64; m <<= 1) {
    s += __shfl_xor(s, m, 64);
    ss += __shfl_xor(ss, m, 64);
  }
  __shared__ float rs_[4], rss_[4];
  if ((tid & 63) == 0) { rs_[tid >> 6] = s; rss_[tid >> 6] = ss; }
  __syncthreads();
  s = rs_[0] + rs_[1] + rs_[2] + rs_[3];
  ss = rss_[0] + rss_[1] + rss_[2] + rss_[3];
  float mu = s * (1.f / DIP);
  float var = ss * (1.f / DIP) - mu * mu;
  float rstd = rsqrtf(var + EPSF);
  unsigned short* oh = ipnh + (long)r * DIP;
  unsigned short* ol = ipnl + (long)r * DIP;
#pragma unroll
  for (int i = 0; i < 5; i++) {
    int c = tid + i * 256;
    float o = (v[i] - mu) * rstd * (1.f + e[DIP + c]) + e[c];
    unsigned short hb = f2bf(o);
    oh[c] = hb;
    ol[c] = f2bf(o - bf2f(hb));
  }
}

// ---------------- Kernel 3: img K (RMS) -> Kb bf16, img V -> Vt bf16 (tiled) --
// Kb[H][LK][128]; Vt tiled: [H][LK/32 tiles][128 d][32 cols] (8 KB contiguous tiles).
__global__ __launch_bounds__(256) void prep_kernel(
    const float* __restrict__ k_in, const float* __restrict__ v_in,
    const float* __restrict__ g_k,
    unsigned short* __restrict__ Kb, unsigned short* __restrict__ Vt) {
  __shared__ unsigned short Vls[128][33];
  int h = blockIdx.y, l0 = blockIdx.x * 32;
  int tid = threadIdx.x;
  int r = tid >> 3, c = tid & 7;   // 8 threads/row, 16 elems each
  const float* ksrc = k_in + (long)(l0 + r) * DM + h * Dh + c * 16;
  const float* vsrc = v_in + (long)(l0 + r) * DM + h * Dh + c * 16;
  float kv[16], vv[16];
  float ssq = 0.f;
#pragma unroll
  for (int i = 0; i < 4; i++) {
    float4 a = *(const float4*)(ksrc + i * 4);
    float4 b = *(const float4*)(vsrc + i * 4);
    kv[i*4+0]=a.x; kv[i*4+1]=a.y; kv[i*4+2]=a.z; kv[i*4+3]=a.w;
    vv[i*4+0]=b.x; vv[i*4+1]=b.y; vv[i*4+2]=b.z; vv[i*4+3]=b.w;
    ssq += a.x*a.x + a.y*a.y + a.z*a.z + a.w*a.w;
  }
  ssq += __shfl_xor(ssq, 1, 8);
  ssq += __shfl_xor(ssq, 2, 8);
  ssq += __shfl_xor(ssq, 4, 8);
  float rstd = rsqrtf(ssq * (1.f / Dh) + EPSF);
  unsigned short kb[16];
#pragma unroll
  for (int i = 0; i < 16; i++) kb[i] = f2bf(kv[i] * rstd * g_k[c * 16 + i]);
  unsigned short* kdst = Kb + ((long)h * LK + l0 + r) * Dh + c * 16;
  *(uint4*)(kdst) = *(uint4*)(kb);
  *(uint4*)(kdst + 8) = *(uint4*)(kb + 8);
  // transpose V through LDS
#pragma unroll
  for (int i = 0; i < 16; i++) Vls[c * 16 + i][r] = f2bf(vv[i]);
  __syncthreads();
  if (tid < 128) {   // one thread per d-row: 64B store, tile-contiguous dest
    int d = tid;
    unsigned short ov[32];
#pragma unroll
    for (int j = 0; j < 32; j++) ov[j] = Vls[d][j];
    unsigned short* vdst = Vt + ((long)h * 80 + (l0 >> 5)) * 4096 + d * 32;
    *(uint4*)(vdst)      = *(uint4*)(ov);
    *(uint4*)(vdst + 8)  = *(uint4*)(ov + 8);
    *(uint4*)(vdst + 16) = *(uint4*)(ov + 16);
    *(uint4*)(vdst + 24) = *(uint4*)(ov + 24);
  }
}

// ---------------- Kernel 4: ip projections via split-bf16 MFMA (2-phase dbuf) --
__global__ __launch_bounds__(256) void proj_kernel(
    const unsigned short* __restrict__ Ah, const unsigned short* __restrict__ Al,
    const float* __restrict__ Wk, const float* __restrict__ Wv,
    const float* __restrict__ g_ipk,
    unsigned short* __restrict__ Kb, unsigned short* __restrict__ Vt) {
  // per-buf layout (ushort offsets): Ahs 0, Als 2048, Whs 4096, Wls 8192; buf stride 12288
  __shared__ __align__(16) unsigned short lds_u[24576];   // 48 KB (double-buffered)
  const float* W = blockIdx.z ? Wv : Wk;
  int h = blockIdx.y;
  int m0 = blockIdx.x * 64;
  int tid = threadIdx.x;
  int w = tid >> 6, lane = tid & 63;
  int m = lane & 15, quad = lane >> 4;

  const float* wrow = W + (long)(h * Dh + (tid & 127)) * DIP + ((tid >> 7) << 3);
  const unsigned short* garow_h = Ah + (long)(m0 + lane) * DIP + w * 8;
  const unsigned short* garow_l = Al + (long)(m0 + lane) * DIP + w * 8;

  f32x4 acc[8];
#pragma unroll
  for (int i = 0; i < 8; i++) acc[i] = (f32x4){0.f, 0.f, 0.f, 0.f};

  float4 wa = *(const float4*)(wrow);
  float4 wb = *(const float4*)(wrow + 4);
  float4 wc = *(const float4*)(wrow + 16);
  float4 wd = *(const float4*)(wrow + 20);

  auto stagek = [&](int b, int k0) {
    float cur[16] = {wa.x, wa.y, wa.z, wa.w, wb.x, wb.y, wb.z, wb.w,
                     wc.x, wc.y, wc.z, wc.w, wd.x, wd.y, wd.z, wd.w};
    if (k0 + 32 < DIP) {   // prefetch next K-step's W regs (hidden under compute)
      wa = *(const float4*)(wrow + k0 + 32);
      wb = *(const float4*)(wrow + k0 + 36);
      wc = *(const float4*)(wrow + k0 + 48);
      wd = *(const float4*)(wrow + k0 + 52);
    }
    // hi/lo split via packed bf16 converts (RNE, bit-identical to f2bf path)
    unsigned hw[8], lw[8];
#pragma unroll
    for (int i = 0; i < 8; i++) {
      float a = cur[2 * i], b = cur[2 * i + 1];
      unsigned hword = cvt_pk_bf16(a, b);
      union { unsigned u; float f; } la, lb;
      la.u = hword << 16;
      lb.u = hword & 0xffff0000u;
      unsigned lword = cvt_pk_bf16(a - la.f, b - lb.f);
      hw[i] = hword; lw[i] = lword;
    }
    unsigned short* AhsB = lds_u + b * 12288;
    unsigned short* AlsB = AhsB + 2048;
    unsigned short* WhsB = AhsB + 4096;
    unsigned short* WlsB = AhsB + 8192;
    __builtin_amdgcn_global_load_lds((gu32*)(garow_h + k0), (lu32*)(AhsB + w * 512), 16, 0, 0);
    __builtin_amdgcn_global_load_lds((gu32*)(garow_l + k0), (lu32*)(AlsB + w * 512), 16, 0, 0);
    uint4 q;
    q.x = hw[0]; q.y = hw[1]; q.z = hw[2]; q.w = hw[3];
    *(uint4*)(WhsB + tid * 8) = q;
    q.x = lw[0]; q.y = lw[1]; q.z = lw[2]; q.w = lw[3];
    *(uint4*)(WlsB + tid * 8) = q;
    q.x = hw[4]; q.y = hw[5]; q.z = hw[6]; q.w = hw[7];
    *(uint4*)(WhsB + (tid + 256) * 8) = q;
    q.x = lw[4]; q.y = lw[5]; q.z = lw[6]; q.w = lw[7];
    *(uint4*)(WlsB + (tid + 256) * 8) = q;
  };

  stagek(0, 0);
  __syncthreads();
  int buf = 0;
#pragma unroll 1
  for (int k0 = 0; k0 < DIP; k0 += 32) {
    if (k0 + 32 < DIP) stagek(buf ^ 1, k0 + 32);  // issue next tile before compute
    unsigned short* AhsB = lds_u + buf * 12288;
    unsigned short* AlsB = AhsB + 2048;
    unsigned short* WhsB = AhsB + 4096;
    unsigned short* WlsB = AhsB + 8192;
    bf16x8 ahf = *(const bf16x8*)(AhsB + ((quad << 6) + (w << 4) + m) * 8);
    bf16x8 alf = *(const bf16x8*)(AlsB + ((quad << 6) + (w << 4) + m) * 8);
#pragma unroll
    for (int nt = 0; nt < 8; nt++) {
      bf16x8 bhf = *(const bf16x8*)(WhsB + ((quad << 7) + (nt << 4) + m) * 8);
      bf16x8 blf = *(const bf16x8*)(WlsB + ((quad << 7) + (nt << 4) + m) * 8);
      acc[nt] = __builtin_amdgcn_mfma_f32_16x16x32_bf16(ahf, bhf, acc[nt], 0, 0, 0);
      acc[nt] = __builtin_amdgcn_mfma_f32_16x16x32_bf16(ahf, blf, acc[nt], 0, 0, 0);
      acc[nt] = __builtin_amdgcn_mfma_f32_16x16x32_bf16(alf, bhf, acc[nt], 0, 0, 0);
    }
    __syncthreads();   // drains this iter's loads (hidden under the MFMAs above)
    buf ^= 1;
  }

  if (blockIdx.z == 0) {
    float gkv[8];
#pragma unroll
    for (int nt = 0; nt < 8; nt++) gkv[nt] = g_ipk[nt * 16 + m];
#pragma unroll
    for (int r = 0; r < 4; r++) {
      float ssq = 0.f;
#pragma unroll
      for (int nt = 0; nt < 8; nt++) ssq += acc[nt][r] * acc[nt][r];
      ssq += __shfl_xor(ssq, 1, 16);
      ssq += __shfl_xor(ssq, 2, 16);
      ssq += __shfl_xor(ssq, 4, 16);
      ssq += __shfl_xor(ssq, 8, 16);
      float rstd = rsqrtf(ssq * (1.f / Dh) + EPSF);
      long row = (long)h * LK + LIMG + m0 + w * 16 + quad * 4 + r;
#pragma unroll
      for (int nt = 0; nt < 8; nt++)
        Kb[row * Dh + nt * 16 + m] = f2bf(acc[nt][r] * rstd * gkv[nt]);
    }
  } else {
    // tiled Vt: [h][tile][128 d][32 cols]; rows l0q..l0q+3 are contiguous cols
    int l0q = LIMG + m0 + w * 16 + quad * 4;
    unsigned short* vbase = Vt + ((long)h * 80 + (l0q >> 5)) * 4096 + (l0q & 31);
#pragma unroll
    for (int nt = 0; nt < 8; nt++) {
      ushort4 o;
      o.x = f2bf(acc[nt][0]); o.y = f2bf(acc[nt][1]);
      o.z = f2bf(acc[nt][2]); o.w = f2bf(acc[nt][3]);
      *(ushort4*)(vbase + (nt * 16 + m) * 32) = o;
    }
  }
}

// ---------------- Kernel 5: MFMA flash attention ----------------
// BQ=64, grid 768 (3 blocks/CU), unroll x2, hoisted stage pointers.
// Softmax chain cuts: speculative exp (threshold check runs in parallel),
// v_cvt_pk_bf16_f32 for P conversion+pack, l-sum reduction deferred to epilogue.
__global__ __launch_bounds__(256, 4) void flash_kernel(
    const float* __restrict__ q_in, const float* __restrict__ g_q,
    const unsigned short* __restrict__ Kb, const unsigned short* __restrict__ Vt,
    float* __restrict__ out) {
  __shared__ __align__(16) unsigned char lds[16384 + 16384 + 5120];  // 37.9 KB
  unsigned short* Ks = (unsigned short*)lds;            // [2][32][16g] XOR-16 swz
  unsigned short* Vs = (unsigned short*)(lds + 16384);  // [2][128][4g] XOR-(d>>1) swz
  unsigned short* Ps = (unsigned short*)(lds + 32768);  // [4 waves][16][40]
  int tid = threadIdx.x;
  int w = tid >> 6, lid = tid & 63;
  int m = lid & 15, quad = lid >> 4;
  int id = blockIdx.x;
  int sidx = id >> 3;
  int h = (id & 7) * 3 + (sidx >> 5);   // XCD (id%8) gets heads 3x..3x+2
  int q0 = (sidx & 31) * 64;
  int qrow = q0 + w * 16 + m;

  // ---- Q: load fp32, RMS over 128 (quad lanes hold disjoint d), g_q, -> A-frags ----
  bf16x8 aq[4];
  {
    float qf[4][8];
    float ssq = 0.f;
    const float* qsrc = q_in + (long)qrow * DM + h * Dh + quad * 8;
#pragma unroll
    for (int ks = 0; ks < 4; ks++) {
      float4 a = *(const float4*)(qsrc + ks * 32);
      float4 b = *(const float4*)(qsrc + ks * 32 + 4);
      qf[ks][0]=a.x; qf[ks][1]=a.y; qf[ks][2]=a.z; qf[ks][3]=a.w;
      qf[ks][4]=b.x; qf[ks][5]=b.y; qf[ks][6]=b.z; qf[ks][7]=b.w;
      ssq += a.x*a.x + a.y*a.y + a.z*a.z + a.w*a.w;
      ssq += b.x*b.x + b.y*b.y + b.z*b.z + b.w*b.w;
    }
    ssq += __shfl_xor(ssq, 16, 64);
    ssq += __shfl_xor(ssq, 32, 64);
    float rstd = rsqrtf(ssq * (1.f / Dh) + EPSF);
    const float* gq = g_q + quad * 8;
#pragma unroll
    for (int ks = 0; ks < 4; ks++) {
      float4 ga = *(const float4*)(gq + ks * 32);
      float4 gb = *(const float4*)(gq + ks * 32 + 4);
      float gg[8] = {ga.x, ga.y, ga.z, ga.w, gb.x, gb.y, gb.z, gb.w};
#pragma unroll
      for (int j = 0; j < 8; j++)
        aq[ks][j] = (short)f2bf(qf[ks][j] * rstd * gg[j]);
    }
  }

  const unsigned short* KbH = Kb + (long)h * LK * Dh;
  const unsigned short* VtH = Vt + (long)h * 80 * 4096;
  unsigned short* Pw = Ps + w * 640;

  f32x4 acc_o[8];
#pragma unroll
  for (int i = 0; i < 8; i++) acc_o[i] = (f32x4){0.f, 0.f, 0.f, 0.f};
  float mrun = -INFINITY;   // per-lane: q-row = m (row-uniform across quads)
  float lrun = 0.f;         // per-lane PARTIAL sum (reduced across quads at end)

  // ---- hoisted per-lane stage pointers (advance 8192 B per tile) ----
  int s0 = w * 128 + lid, s1 = s0 + 64;
  int rK0 = s0 >> 4, cK0 = (s0 & 15) ^ (rK0 & 15);
  int rK1 = s1 >> 4, cK1 = (s1 & 15) ^ (rK1 & 15);
  const unsigned short* pK0 = KbH + (long)rK0 * Dh + cK0 * 8;
  const unsigned short* pK1 = KbH + (long)rK1 * Dh + cK1 * 8;
  int dV0 = s0 >> 2, cV0 = (s0 & 3) ^ ((dV0 >> 1) & 3);
  int dV1 = s1 >> 2, cV1 = (s1 & 3) ^ ((dV1 >> 1) & 3);
  const unsigned short* pV0 = VtH + dV0 * 32 + cV0 * 8;
  const unsigned short* pV1 = VtH + dV1 * 32 + cV1 * 8;

  auto stage = [&](int b) {
    unsigned short* KsB = Ks + b * 4096;
    unsigned short* VsB = Vs + b * 4096;
    __builtin_amdgcn_global_load_lds((gu32*)pK0, (lu32*)(KsB + (w * 128) * 8), 16, 0, 0);
    __builtin_amdgcn_global_load_lds((gu32*)pK1, (lu32*)(KsB + (w * 128 + 64) * 8), 16, 0, 0);
    __builtin_amdgcn_global_load_lds((gu32*)pV0, (lu32*)(VsB + (w * 128) * 8), 16, 0, 0);
    __builtin_amdgcn_global_load_lds((gu32*)pV1, (lu32*)(VsB + (w * 128 + 64) * 8), 16, 0, 0);
    pK0 += 4096; pK1 += 4096;   // next K tile: 32 rows x 128
    pV0 += 4096; pV1 += 4096;   // next V tile: 128 x 32
  };

  auto compute = [&](const unsigned short* KsB, const unsigned short* VsB) {
    // ---- S^T = K Q^T : lane (m,quad) -> q=m, k = t*16 + quad*4 + r ----
    f32x4 sc[2];
    sc[0] = (f32x4){0.f, 0.f, 0.f, 0.f};
    sc[1] = (f32x4){0.f, 0.f, 0.f, 0.f};
    __builtin_amdgcn_s_setprio(1);
#pragma unroll
    for (int t = 0; t < 2; t++)
#pragma unroll
      for (int ks = 0; ks < 4; ks++) {
        int rr = t * 16 + m;
        int g = (ks * 4 + quad) ^ m;
        bf16x8 bk = *(const bf16x8*)(KsB + rr * 128 + g * 8);
        sc[t] = __builtin_amdgcn_mfma_f32_16x16x32_bf16(bk, aq[ks], sc[t], 0, 0, 0);
      }
    __builtin_amdgcn_s_setprio(0);

    float pv[8] = {sc[0][0], sc[0][1], sc[0][2], sc[0][3],
                   sc[1][0], sc[1][1], sc[1][2], sc[1][3]};
    // speculative exp against the CURRENT running max (defer-max common path);
    // the threshold check below runs concurrently, off the critical path.
    float p[8];
#pragma unroll
    for (int j = 0; j < 8; j++) p[j] = EXP2F((pv[j] - mrun) * C2EXP);

    float t0 = fmaxf(fmaxf(pv[0], pv[1]), fmaxf(pv[2], pv[3]));
    float t1 = fmaxf(fmaxf(pv[4], pv[5]), fmaxf(pv[6], pv[7]));
    float tmax = fmaxf(t0, t1);
    tmax = fmaxf(tmax, __shfl_xor(tmax, 16, 64));
    tmax = fmaxf(tmax, __shfl_xor(tmax, 32, 64));
    if (!__all(tmax <= mrun + THRU)) {   // rare rescale path (wave-uniform)
      float mnew = fmaxf(mrun, tmax);
      float al = EXP2F((mrun - mnew) * C2EXP);
      mrun = mnew;
#pragma unroll
      for (int j = 0; j < 8; j++) p[j] = EXP2F((pv[j] - mrun) * C2EXP);
      lrun *= al;
      float alr[4];
#pragma unroll
      for (int r = 0; r < 4; r++) alr[r] = __shfl(al, quad * 4 + r, 16);
#pragma unroll
      for (int dt = 0; dt < 8; dt++) {
        acc_o[dt][0] *= alr[0]; acc_o[dt][1] *= alr[1];
        acc_o[dt][2] *= alr[2]; acc_o[dt][3] *= alr[3];
      }
    }
    lrun += (p[0] + p[1]) + (p[2] + p[3]) + (p[4] + p[5]) + (p[6] + p[7]);

    // ---- P: packed bf16 converts -> LDS -> PV A-fragment ----
    uint2 pka, pkb;
    pka.x = cvt_pk_bf16(p[0], p[1]);
    pka.y = cvt_pk_bf16(p[2], p[3]);
    pkb.x = cvt_pk_bf16(p[4], p[5]);
    pkb.y = cvt_pk_bf16(p[6], p[7]);
    *(uint2*)(Pw + m * 40 + quad * 4) = pka;
    *(uint2*)(Pw + m * 40 + 16 + quad * 4) = pkb;
    bf16x8 ap = *(const bf16x8*)(Pw + m * 40 + quad * 8);

    __builtin_amdgcn_s_setprio(1);
#pragma unroll
    for (int dt = 0; dt < 8; dt++) {
      bf16x8 bv = *(const bf16x8*)(VsB + ((dt * 16 + m) * 4 + (quad ^ ((m >> 1) & 3))) * 8);
      acc_o[dt] = __builtin_amdgcn_mfma_f32_16x16x32_bf16(ap, bv, acc_o[dt], 0, 0, 0);
    }
    __builtin_amdgcn_s_setprio(0);
  };

  stage(0);
  __syncthreads();
#pragma unroll 1
  for (int jt = 0; jt < LK / 32; jt += 2) {
    stage(1);                         // prefetch odd tile
    compute(Ks, Vs);                  // even tile (buf 0, static)
    __syncthreads();                  // drains buf-1 prefetch
    if (jt + 2 < LK / 32) stage(0);   // prefetch next even tile
    compute(Ks + 4096, Vs + 4096);    // odd tile (buf 1, static)
    __syncthreads();                  // drains buf-0 prefetch
  }

  // ---- epilogue: reduce deferred l-sums across quads, then normalize ----
  lrun += __shfl_xor(lrun, 16, 64);
  lrun += __shfl_xor(lrun, 32, 64);
  float inv = 1.f / lrun;
  float ilr[4];
#pragma unroll
  for (int r = 0; r < 4; r++) ilr[r] = __shfl(inv, quad * 4 + r, 16);
#pragma unroll
  for (int dt = 0; dt < 8; dt++)
#pragma unroll
    for (int r = 0; r < 4; r++)
      out[(long)(q0 + w * 16 + quad * 4 + r) * DM + h * Dh + dt * 16 + m] =
          acc_o[dt][r] * ilr[r];
}

// ---------------- launch ----------------
extern "C" void kernel_launch(void* const* d_in, const int* in_sizes, int n_in,
                              void* d_out, int out_size, void* d_ws, size_t ws_size,
                              hipStream_t stream) {
  const float* ip_hidden = (const float*)d_in[0];
  const float* img_q     = (const float*)d_in[1];
  const float* img_k     = (const float*)d_in[2];
  const float* img_v     = (const float*)d_in[3];
  const float* t_emb     = (const float*)d_in[4];
  const float* w_ada     = (const float*)d_in[5];
  const float* b_ada     = (const float*)d_in[6];
  const float* w_k_ip    = (const float*)d_in[7];
  const float* w_v_ip    = (const float*)d_in[8];
  const float* g_q       = (const float*)d_in[9];
  const float* g_k       = (const float*)d_in[10];
  const float* g_ipk     = (const float*)d_in[11];

  char* base = (char*)d_ws;
  float* e = (float*)base;
  unsigned short* ipnh = (unsigned short*)(base + 16384);
  unsigned short* ipnl = (unsigned short*)(base + 1327104);
  unsigned short* Kb   = (unsigned short*)(base + 2637824);
  unsigned short* Vt   = Kb + (size_t)H * LK * Dh;
  float* out = (float*)d_out;

  ada_kernel<<<2 * DIP, 256, 0, stream>>>(t_emb, w_ada, b_ada, e);
  adaln_kernel<<<LIP, 256, 0, stream>>>(ip_hidden, e, ipnh, ipnl);
  prep_kernel<<<dim3(LIMG / 32, H), 256, 0, stream>>>(img_k, img_v, g_k, Kb, Vt);
  proj_kernel<<<dim3(LIP / 64, H, 2), 256, 0, stream>>>(ipnh, ipnl, w_k_ip, w_v_ip,
                                                        g_ipk, Kb, Vt);
  flash_kernel<<<dim3(768), 256, 0, stream>>>(img_q, g_q, Kb, Vt, out);
}